// Round 1
// baseline (6972.090 us; speedup 1.0000x reference)
//
#include <hip/hip_runtime.h>
#include <math.h>

#define T_STEPS 512
#define B_SZ 8
#define D_SZ 512
#define N_SZ 64

// ---------------------------------------------------------------------------
// fast tanh via hardware exp; clamp avoids inf/inf NaN
__device__ __forceinline__ float tanh_fast(float x) {
    float cx = fminf(30.f, fmaxf(-30.f, x));
    float e = __expf(2.f * cx);
    return (e - 1.f) / (e + 1.f);
}

// ---------------------------------------------------------------------------
// proj_gemm: C[m,n] = sum_d A[m,d] * W[n,d] (+ bias[n])
// A: [M, D] row-major; W: [Nc, D] row-major; C: [M, Nc] row-major.
// BM=BN=64, BK=16, 256 threads, 4x4 micro-tile per thread.
__global__ __launch_bounds__(256)
void proj_gemm(const float* __restrict__ A, const float* __restrict__ W,
               const float* __restrict__ bias, float* __restrict__ C,
               int M, int Nc, int D) {
    __shared__ float As[16][64];
    __shared__ float Ws[16][64];
    const int m0 = blockIdx.x * 64;
    const int n0 = blockIdx.y * 64;
    const int tid = threadIdx.x;
    const int tx = tid & 15;        // n direction
    const int ty = tid >> 4;        // m direction
    const int lr = tid >> 2;        // 0..63 row within tile (for loading)
    const int lk = (tid & 3) * 4;   // k offset within tile

    float acc[4][4];
#pragma unroll
    for (int i = 0; i < 4; i++)
#pragma unroll
        for (int j = 0; j < 4; j++) acc[i][j] = 0.f;

    for (int kk = 0; kk < D; kk += 16) {
        float4 av = *(const float4*)&A[(size_t)(m0 + lr) * D + kk + lk];
        float4 wv = *(const float4*)&W[(size_t)(n0 + lr) * D + kk + lk];
        __syncthreads();
        As[lk + 0][lr] = av.x; As[lk + 1][lr] = av.y;
        As[lk + 2][lr] = av.z; As[lk + 3][lr] = av.w;
        Ws[lk + 0][lr] = wv.x; Ws[lk + 1][lr] = wv.y;
        Ws[lk + 2][lr] = wv.z; Ws[lk + 3][lr] = wv.w;
        __syncthreads();
#pragma unroll
        for (int k = 0; k < 16; k++) {
            float a0 = As[k][ty * 4 + 0], a1 = As[k][ty * 4 + 1];
            float a2 = As[k][ty * 4 + 2], a3 = As[k][ty * 4 + 3];
            float w0 = Ws[k][tx * 4 + 0], w1 = Ws[k][tx * 4 + 1];
            float w2 = Ws[k][tx * 4 + 2], w3 = Ws[k][tx * 4 + 3];
            acc[0][0] += a0 * w0; acc[0][1] += a0 * w1; acc[0][2] += a0 * w2; acc[0][3] += a0 * w3;
            acc[1][0] += a1 * w0; acc[1][1] += a1 * w1; acc[1][2] += a1 * w2; acc[1][3] += a1 * w3;
            acc[2][0] += a2 * w0; acc[2][1] += a2 * w1; acc[2][2] += a2 * w2; acc[2][3] += a2 * w3;
            acc[3][0] += a3 * w0; acc[3][1] += a3 * w1; acc[3][2] += a3 * w2; acc[3][3] += a3 * w3;
        }
    }

    float b0 = 0.f, b1 = 0.f, b2 = 0.f, b3 = 0.f;
    if (bias) {
        b0 = bias[n0 + tx * 4 + 0]; b1 = bias[n0 + tx * 4 + 1];
        b2 = bias[n0 + tx * 4 + 2]; b3 = bias[n0 + tx * 4 + 3];
    }
#pragma unroll
    for (int i = 0; i < 4; i++) {
        float4 ov;
        ov.x = acc[i][0] + b0; ov.y = acc[i][1] + b1;
        ov.z = acc[i][2] + b2; ov.w = acc[i][3] + b3;
        *(float4*)&C[(size_t)(m0 + ty * 4 + i) * Nc + n0 + tx * 4] = ov;
    }
}

// ---------------------------------------------------------------------------
// scan_kernel: one workgroup per batch b (8 WGs, 512 threads).
// Thread layout: n = tid>>3 (row 0..63), c = tid&7, d-chunk = c*64 .. c*64+63.
// State S[b,n,d] lives in 64 VGPRs per thread.
__global__ __launch_bounds__(512)
void scan_kernel(const float* __restrict__ kp, const float* __restrict__ qp,
                 const float* __restrict__ wxp, const float* __restrict__ axp,
                 const float* __restrict__ S0, const float* __restrict__ W_r,
                 float* __restrict__ out_y, float* __restrict__ out_S) {
    const int b = blockIdx.x;
    const int tid = threadIdx.x;
    const int n = tid >> 3;
    const int c = tid & 7;
    const int d0 = c * 64;

    __shared__ float Wr_s[64 * 65];   // row stride 65: breaks 8-way bank conflict
    __shared__ float sh_r[64];

    // stage W_r [N,N] into LDS (constant across steps)
    for (int i = tid; i < 64 * 64; i += 512) {
        int r = i >> 6, col = i & 63;
        Wr_s[r * 65 + col] = W_r[i];
    }

    // load S0 into registers, and emit S[0] = S0
    float s[64];
    {
        const float* s0p = S0 + ((size_t)b * N_SZ + n) * D_SZ + d0;
        float* so = out_S + ((size_t)b * N_SZ + n) * D_SZ + d0;  // t=0 slice
#pragma unroll
        for (int j = 0; j < 16; j++) {
            float4 v4 = *(const float4*)&s0p[j * 4];
            s[j * 4 + 0] = v4.x; s[j * 4 + 1] = v4.y;
            s[j * 4 + 2] = v4.z; s[j * 4 + 3] = v4.w;
            *(float4*)&so[j * 4] = v4;
        }
    }
    __syncthreads();  // Wr_s ready

    for (int t = 0; t < T_STEPS; t++) {
        const size_t tb = (size_t)t * B_SZ + b;
        // ---- load k_t chunk into registers ----
        float kr[64];
        {
            const float* kt = kp + tb * D_SZ + d0;
#pragma unroll
            for (int j = 0; j < 16; j++) {
                float4 kv = *(const float4*)&kt[j * 4];
                kr[j * 4 + 0] = kv.x; kr[j * 4 + 1] = kv.y;
                kr[j * 4 + 2] = kv.z; kr[j * 4 + 3] = kv.w;
            }
        }
        // ---- Sk[n] = S[n,:] . k ----
        float sk = 0.f;
#pragma unroll
        for (int j = 0; j < 64; j++) sk += s[j] * kr[j];
        sk += __shfl_xor(sk, 1, 64);
        sk += __shfl_xor(sk, 2, 64);
        sk += __shfl_xor(sk, 4, 64);
        float retr = tanh_fast(sk);
        if (c == 0) sh_r[n] = retr;
        __syncthreads();

        // ---- v[n] = tanh( sum_m retr[m]*W_r[n,m] + wx + b ) ----
        float vp = 0.f;
#pragma unroll
        for (int j = 0; j < 8; j++) {
            int m = c * 8 + j;
            vp += sh_r[m] * Wr_s[n * 65 + m];
        }
        vp += __shfl_xor(vp, 1, 64);
        vp += __shfl_xor(vp, 2, 64);
        vp += __shfl_xor(vp, 4, 64);
        float wx = wxp[tb * N_SZ + n];   // bias b folded in by proj_gemm
        float ax = axp[tb * N_SZ + n];   // bias b_alpha folded in
        float v = tanh_fast(vp + wx);
        float alpha = 1.f / (1.f + __expf(-ax));
        float g = (1.f - alpha) * v;

        // ---- state update: S = alpha*S + g*k ----
#pragma unroll
        for (int j = 0; j < 64; j++) s[j] = alpha * s[j] + g * kr[j];

        // ---- write S[t+1] ----
        {
            float* so = out_S + (((size_t)(t + 1) * B_SZ + b) * N_SZ + n) * D_SZ + d0;
#pragma unroll
            for (int j = 0; j < 16; j++) {
                float4 sv;
                sv.x = s[j * 4 + 0]; sv.y = s[j * 4 + 1];
                sv.z = s[j * 4 + 2]; sv.w = s[j * 4 + 3];
                *(float4*)&so[j * 4] = sv;
            }
        }

        // ---- y[n] = tanh( S_new[n,:] . q ) ----
        float yp = 0.f;
        {
            const float* qt = qp + tb * D_SZ + d0;
#pragma unroll
            for (int j = 0; j < 16; j++) {
                float4 qv = *(const float4*)&qt[j * 4];
                yp += s[j * 4 + 0] * qv.x + s[j * 4 + 1] * qv.y +
                      s[j * 4 + 2] * qv.z + s[j * 4 + 3] * qv.w;
            }
        }
        yp += __shfl_xor(yp, 1, 64);
        yp += __shfl_xor(yp, 2, 64);
        yp += __shfl_xor(yp, 4, 64);
        if (c == 0) out_y[tb * N_SZ + n] = tanh_fast(yp);

        __syncthreads();  // protect sh_r for next iteration
    }
}

// ---------------------------------------------------------------------------
extern "C" void kernel_launch(void* const* d_in, const int* in_sizes, int n_in,
                              void* d_out, int out_size, void* d_ws, size_t ws_size,
                              hipStream_t stream) {
    const float* x       = (const float*)d_in[0];  // [T,B,D]
    const float* S0      = (const float*)d_in[1];  // [B,N,D]
    const float* W_k     = (const float*)d_in[2];  // [D,D]
    const float* W_q     = (const float*)d_in[3];  // [D,D]
    const float* W_x     = (const float*)d_in[4];  // [N,D]
    const float* W_r     = (const float*)d_in[5];  // [N,N]
    const float* b       = (const float*)d_in[6];  // [N]
    const float* W_alpha = (const float*)d_in[7];  // [N,D]
    const float* b_alpha = (const float*)d_in[8];  // [N]

    float* out_y = (float*)d_out;                              // [T,B,N]
    float* out_S = out_y + (size_t)T_STEPS * B_SZ * N_SZ;      // [T+1,B,N,D]

    const int M = T_STEPS * B_SZ;  // 4096
    float* kp  = (float*)d_ws;                 // [M, D]
    float* qp  = kp + (size_t)M * D_SZ;        // [M, D]
    float* wxp = qp + (size_t)M * D_SZ;        // [M, N]  (b folded)
    float* axp = wxp + (size_t)M * N_SZ;       // [M, N]  (b_alpha folded)

    // projections
    {
        dim3 blk(256);
        dim3 gK(M / 64, D_SZ / 64);
        proj_gemm<<<gK, blk, 0, stream>>>(x, W_k, nullptr, kp, M, D_SZ, D_SZ);
        proj_gemm<<<gK, blk, 0, stream>>>(x, W_q, nullptr, qp, M, D_SZ, D_SZ);
        dim3 gN(M / 64, N_SZ / 64);
        proj_gemm<<<gN, blk, 0, stream>>>(x, W_x, b, wxp, M, N_SZ, D_SZ);
        proj_gemm<<<gN, blk, 0, stream>>>(x, W_alpha, b_alpha, axp, M, N_SZ, D_SZ);
    }

    // sequential scan: one workgroup per batch
    scan_kernel<<<dim3(B_SZ), dim3(512), 0, stream>>>(
        kp, qp, wxp, axp, S0, W_r, out_y, out_S);
}